// Round 11
// baseline (306.191 us; speedup 1.0000x reference)
//
#include <hip/hip_runtime.h>
#include <cmath>

typedef __attribute__((ext_vector_type(4))) float f32x4;
typedef __attribute__((ext_vector_type(8))) _Float16 f16x8;
typedef __attribute__((ext_vector_type(4))) _Float16 f16x4;
typedef __attribute__((ext_vector_type(4))) unsigned int u32x4;

#define B_SZ 16
#define Q_SZ 2048
#define K_SZ 2048
#define D_SZ 128
#define BQ   128     // q-rows per block (4 waves x 32): halves tile-units vs 64
#define BKT  64      // keys per k-tile
#define SCL  0.08838834764831845f   // fp32(1/sqrt(128))

// async global->LDS, 16B/lane: LDS dest = wave-uniform base + lane*16
#define GLDS16(g, s) __builtin_amdgcn_global_load_lds(                      \
    (const __attribute__((address_space(1))) unsigned int*)(g),             \
    (__attribute__((address_space(3))) unsigned int*)(s), 16, 0, 0)

// pack two f32 -> one u32 of 2 f16 (RNE, matches previous (_Float16) casts)
static __device__ inline unsigned pk16(float a, float b) {
  unsigned short ha = __builtin_bit_cast(unsigned short, (_Float16)a);
  unsigned short hb = __builtin_bit_cast(unsigned short, (_Float16)b);
  return (unsigned)ha | ((unsigned)hb << 16);
}

// ---------------------------------------------------------------------------
// prep_all: fused K-split + V-transpose + cnt reset.  (r9 version, verified)
//  blocks [0,2048): K f32 -> Khi/Klo f16, row 256B, 16B groups XOR-swizzled
//    by (key&7).  hi = RNE f16, lo = (x-hi)*2048 (exact pow2 scale).
//  blocks [2048,2560): V f32 -> Vt f16 [b][d][k] (4KB rows), per-64-key-tile:
//    key dim PI-PERMUTED (pos(c,q1,q0,j2,r1,r0) holds key(c,j2,q1,q0,r1,r0))
//    so attn's PV A-fragment needs no P transpose; 16B chunks XOR-swizzled
//    by (d&7).
// ---------------------------------------------------------------------------
__global__ __launch_bounds__(256) void prep_all(
    const float* __restrict__ K, const float* __restrict__ V,
    _Float16* __restrict__ Khi, _Float16* __restrict__ Klo,
    _Float16* __restrict__ Vt, unsigned* __restrict__ cnt)
{
  __shared__ _Float16 tmp[64][136];
  const int tid = threadIdx.x;
  if (cnt && blockIdx.x == 0 && tid == 0) *cnt = 0;
  if (blockIdx.x < 2048) {
    const int gid = blockIdx.x * 256 + tid;
    const int r = gid >> 4;           // global key row = b*2048 + k
    const int g = gid & 15;           // 16B group
    const float* src = K + (size_t)r * D_SZ + g * 8;
    f16x8 hi, lo;
#pragma unroll
    for (int i = 0; i < 8; ++i) {
      float x = src[i];
      _Float16 h = (_Float16)x;
      hi[i] = h;
      lo[i] = (_Float16)((x - (float)h) * 2048.0f);
    }
    const size_t o = (size_t)r * D_SZ + ((g ^ (r & 7)) * 8);
    *(f16x8*)(Khi + o) = hi;
    *(f16x8*)(Klo + o) = lo;
  } else {
    const int vb = blockIdx.x - 2048;
    const int b = vb >> 5;
    const int k0 = (vb & 31) * 64;
    const float* Vb = V + ((size_t)b * K_SZ + k0) * D_SZ;
#pragma unroll
    for (int j = 0; j < 8; ++j) {
      const int e = j * 1024 + tid * 4;
      const int k = e >> 7, d = e & 127;
      const f32x4 v = *(const f32x4*)(Vb + (size_t)k * D_SZ + d);
      f16x4 h;
#pragma unroll
      for (int i = 0; i < 4; ++i) h[i] = (_Float16)v[i];
      *(f16x4*)&tmp[k][d] = h;
    }
    __syncthreads();
#pragma unroll
    for (int i = 0; i < 4; ++i) {
      const int id = i * 256 + tid;
      const int gk = id >> 7, d = id & 127;   // gk = position group (0..7)
      f16x8 o;
#pragma unroll
      for (int jj = 0; jj < 8; ++jj) {
        // position p = gk*8+jj holds actual key kappa (pi-permutation)
        const int kap = ((gk >> 2) << 5) | ((jj >> 2) << 4) | ((gk & 3) << 2) | (jj & 3);
        o[jj] = tmp[kap][d];
      }
      _Float16* dst = Vt + ((size_t)b * D_SZ + d) * K_SZ + k0 + ((gk ^ (d & 7)) * 8);
      *(f16x8*)dst = o;
    }
  }
}

// ---------------------------------------------------------------------------
// attn v11 = r9 skeleton (single-buffer 48KB stage, sorted longest-first
// dynamic queue, plain-store half-split outputs) + BQ=128 compute core
// (r5-verified math): wave owns 32 q-rows (mt=2), so each staged 48KB tile
// serves 2x the q-rows -> total tile-units halve (4096 vs 8192), halving
// total LDS read traffic and stage-DMA volume (the measured dominant costs).
// split=1: 512 tasks = (b,half) unit x 16 qt, walked ntiles-descending;
// grid 768 (3 blocks/CU resident; dynamic queue self-balances, surplus
// blocks exit).  half-0 -> Om/L0, half-1 -> P1/L1 (unique owner, no fences).
// split=0: one (b,qt16) per block, full k-range, normalize in-kernel.
// ---------------------------------------------------------------------------
__global__ __launch_bounds__(256, 3) void attn(
    const float* __restrict__ Qm, const _Float16* __restrict__ KhiG,
    const _Float16* __restrict__ KloG, const _Float16* __restrict__ VtG,
    const int* __restrict__ vlp, float* __restrict__ Om,
    float* __restrict__ P1, float* __restrict__ L0, float* __restrict__ L1,
    unsigned* __restrict__ cnt, const int split)
{
  __shared__ __align__(16) char sm[49152];   // Khi(16K)|Klo(16K)|Vt(16K)
  __shared__ float Ls[128];
  __shared__ int s_task;
  __shared__ signed char ord[32];
  __shared__ int vls[16];

  const int tid  = threadIdx.x;
  const int wave = tid >> 6;
  const int lane = tid & 63;
  const int ln   = lane & 15;
  const int quad = lane >> 4;

  _Float16* smKhi = (_Float16*)sm;
  _Float16* smKlo = (_Float16*)(sm + 16384);
  _Float16* smVt  = (_Float16*)(sm + 32768);

  // ---- once per block: longest-first unit order (deterministic) ----
  if (split) {
    if (tid < 16) vls[tid] = vlp[tid];
    __syncthreads();
    if (tid < 32) {
      const int ub = tid >> 1, uh = tid & 1;
      const int v = vls[ub];
      const int n = uh ? ((v > 1024) ? (v - 1024 + 63) / 64 : 0)
                       : (((v < 1024 ? v : 1024) + 63) / 64);
      int rank = 0;
      for (int u = 0; u < 32; ++u) {
        const int wb = u >> 1, wh = u & 1;
        const int wv = vls[wb];
        const int wn = wh ? ((wv > 1024) ? (wv - 1024 + 63) / 64 : 0)
                          : (((wv < 1024 ? wv : 1024) + 63) / 64);
        rank += (wn > n) || (wn == n && u < tid);
      }
      ord[rank] = (signed char)tid;
    }
    __syncthreads();
  }

  for (;;) {
    int t;
    if (split) {
      if (tid == 0) s_task = (int)atomicAdd(cnt, 1u);
      __syncthreads();
      t = s_task;
      __syncthreads();
      if (t >= 512) return;
    } else {
      t = blockIdx.x;
    }

    int half = 0, b, qt;
    if (split) { const int u = ord[t >> 4]; b = u >> 1; half = u & 1; qt = t & 15; }
    else       { b = t >> 4; qt = t & 15; }
    const int q0     = qt * BQ;
    const int valid  = split ? vls[b] : vlp[b];
    const int kstart = half * 1024;
    const int kend   = split ? min(valid, kstart + 1024) : valid;
    if (kend <= kstart) { if (!split) return; continue; }  // empty half-1
    const int ntiles = (kend - kstart + BKT - 1) / BKT;

    const float* Qb    = Qm + (size_t)b * Q_SZ * D_SZ;
    const char*  gKhiB = (const char*)KhiG + (size_t)b * K_SZ * 256;
    const char*  gKloB = (const char*)KloG + (size_t)b * K_SZ * 256;
    const char*  gVtB  = (const char*)VtG  + (size_t)b * D_SZ * (K_SZ * 2);

    // ---- Q fragments: 2 m-tiles x 4 k-chunks, fp16 hi/lo split ----
    f16x8 qhi[2][4], qlo[2][4];
#pragma unroll
    for (int mt = 0; mt < 2; ++mt) {
      const int qrow = q0 + wave * 32 + mt * 16 + ln;
      const float* srcb = Qb + (size_t)qrow * D_SZ + quad * 8;
#pragma unroll
      for (int c = 0; c < 4; ++c) {
#pragma unroll
        for (int j = 0; j < 8; ++j) {
          float x = srcb[c * 32 + j];
          _Float16 h = (_Float16)x;
          qhi[mt][c][j] = h;
          qlo[mt][c][j] = (_Float16)((x - (float)h) * 2048.0f);
        }
      }
    }

    const f32x4 vzero = {0.f, 0.f, 0.f, 0.f};
    f32x4 accO[2][8];           // [mt][dt]: O[32q][128d] per wave
    float lsum[2] = {0.f, 0.f};
#pragma unroll
    for (int mt = 0; mt < 2; ++mt)
#pragma unroll
      for (int dt = 0; dt < 8; ++dt) accO[mt][dt] = vzero;

    for (int kt = 0; kt < ntiles; ++kt) {
      const int k0g = kstart + kt * BKT;

      if (kt) {                 // B_top: all waves done reading tile kt-1
        asm volatile("s_waitcnt lgkmcnt(0)" ::: "memory");
        __builtin_amdgcn_sched_barrier(0);
        __builtin_amdgcn_s_barrier();
        __builtin_amdgcn_sched_barrier(0);
      }

      // ---- stage tile kt (single buffer; 12 x 1KB chunks per wave) ----
      {
        const char* gh = gKhiB + (size_t)k0g * 256;
        const char* gl = gKloB + (size_t)k0g * 256;
#pragma unroll
        for (int i = 0; i < 4; ++i) {
          const int off = wave * 1024 + i * 4096;
          GLDS16(gh + off + lane * 16, sm + off);
        }
#pragma unroll
        for (int i = 0; i < 4; ++i) {
          const int off = wave * 1024 + i * 4096;
          GLDS16(gl + off + lane * 16, sm + 16384 + off);
        }
#pragma unroll
        for (int i = 0; i < 4; ++i) {
          const int off = wave * 1024 + i * 4096;
          const int a = off + lane * 16;
          const int d = a >> 7, win = a & 127;
          GLDS16(gVtB + (size_t)d * (K_SZ * 2) + (size_t)k0g * 2 + win,
                 sm + 32768 + off);
        }
      }
      asm volatile("s_waitcnt vmcnt(0)" ::: "memory");
      __builtin_amdgcn_sched_barrier(0);
      __builtin_amdgcn_s_barrier();     // B_ready: tile visible to all waves
      __builtin_amdgcn_sched_barrier(0);

      // ---- S^T = K Q^T over all 64 keys, split precision; softmax in reg ----
      f16x8 pa[2][2];           // PV A-frags [mt][hk]
#pragma unroll
      for (int hk = 0; hk < 2; ++hk) {   // key halves of 32 (= PV chunk c)
        f32x4 accM[2][2], accC[2][2];    // [mt][nb2]
#pragma unroll
        for (int mt = 0; mt < 2; ++mt)
#pragma unroll
          for (int nb2 = 0; nb2 < 2; ++nb2) { accM[mt][nb2] = vzero; accC[mt][nb2] = vzero; }
        __builtin_amdgcn_s_setprio(1);
#pragma unroll
        for (int nb2 = 0; nb2 < 2; ++nb2) {
          const int row = (hk * 2 + nb2) * 16 + ln;
          const _Float16* bh_base = smKhi + row * 128;
          const _Float16* bl_base = smKlo + row * 128;
#pragma unroll
          for (int c = 0; c < 4; ++c) {
            const int pg = (((c * 4 + quad) ^ (ln & 7)) * 8);
            const f16x8 bh = *(const f16x8*)(bh_base + pg);
            const f16x8 bl = *(const f16x8*)(bl_base + pg);
#pragma unroll
            for (int mt = 0; mt < 2; ++mt) {
              accM[mt][nb2] = __builtin_amdgcn_mfma_f32_16x16x32_f16(bh, qhi[mt][c], accM[mt][nb2], 0, 0, 0);
              accC[mt][nb2] = __builtin_amdgcn_mfma_f32_16x16x32_f16(bl, qhi[mt][c], accC[mt][nb2], 0, 0, 0);
              accC[mt][nb2] = __builtin_amdgcn_mfma_f32_16x16x32_f16(bh, qlo[mt][c], accC[mt][nb2], 0, 0, 0);
            }
          }
        }
        __builtin_amdgcn_s_setprio(0);

        // fixed-max softmax: p = e^{floor(s/sqrt d)}; masked -> 0; pack to pa
#pragma unroll
        for (int mt = 0; mt < 2; ++mt) {
          u32x4 w;
#pragma unroll
          for (int nb2 = 0; nb2 < 2; ++nb2) {
            float e[4];
#pragma unroll
            for (int r = 0; r < 4; ++r) {
              const int key = k0g + (hk * 2 + nb2) * 16 + quad * 4 + r;
              const float s = accM[mt][nb2][r] + accC[mt][nb2][r] * (1.0f / 2048.0f);
              e[r] = (key < valid) ? __expf(floorf(s * SCL)) : 0.0f;
              lsum[mt] += e[r];
            }
            w[nb2 * 2 + 0] = pk16(e[0], e[1]);
            w[nb2 * 2 + 1] = pk16(e[2], e[3]);
          }
          pa[mt][hk] = __builtin_bit_cast(f16x8, w);   // matches pi-permuted V
        }
      }

      // ---- O += P V : wave does all 128 d-cols for its 32 q-rows ----
      __builtin_amdgcn_s_setprio(1);
#pragma unroll
      for (int c = 0; c < 2; ++c) {
#pragma unroll
        for (int dt = 0; dt < 8; ++dt) {
          const int drow = dt * 16 + ln;
          const int pg = (((c * 4 + quad) ^ (ln & 7)) * 8);
          const f16x8 bf = *(const f16x8*)(smVt + drow * 64 + pg);
#pragma unroll
          for (int mt = 0; mt < 2; ++mt)
            accO[mt][dt] = __builtin_amdgcn_mfma_f32_16x16x32_f16(pa[mt][c], bf, accO[mt][dt], 0, 0, 0);
        }
      }
      __builtin_amdgcn_s_setprio(0);
    }

    // ---- epilogue: reduce l across quads (q = wave*32 + mt*16 + ln) ----
#pragma unroll
    for (int mt = 0; mt < 2; ++mt) {
      float v = lsum[mt];
      v += __shfl_xor(v, 16, 64);
      v += __shfl_xor(v, 32, 64);
      lsum[mt] = v;
    }

    if (split) {
      // plain stores: unique owner per (half,row); finalize = coherence point
      float* Lh = half ? L1 : L0;
      if (lane < 16) {
#pragma unroll
        for (int mt = 0; mt < 2; ++mt)
          Lh[b * Q_SZ + q0 + wave * 32 + mt * 16 + lane] = lsum[mt];
      }
      float* dst = (half ? P1 : Om) + ((size_t)(b * Q_SZ + q0)) * D_SZ;
#pragma unroll
      for (int mt = 0; mt < 2; ++mt)
#pragma unroll
        for (int dt = 0; dt < 8; ++dt)
#pragma unroll
          for (int r = 0; r < 4; ++r)
            dst[(size_t)(wave * 32 + mt * 16 + quad * 4 + r) * D_SZ + dt * 16 + ln] =
                accO[mt][dt][r];
    } else {
      if (lane < 16) {
#pragma unroll
        for (int mt = 0; mt < 2; ++mt)
          Ls[wave * 32 + mt * 16 + lane] = lsum[mt];
      }
      __syncthreads();
      float* Ob = Om + (size_t)b * Q_SZ * D_SZ;
#pragma unroll
      for (int mt = 0; mt < 2; ++mt) {
#pragma unroll
        for (int r = 0; r < 4; ++r) {
          const float inv = 1.0f / Ls[wave * 32 + mt * 16 + quad * 4 + r];
#pragma unroll
          for (int dt = 0; dt < 8; ++dt)
            Ob[(size_t)(q0 + wave * 32 + mt * 16 + quad * 4 + r) * D_SZ + dt * 16 + ln] =
                accO[mt][dt][r] * inv;
        }
      }
    }
    if (!split) return;
  }
}

// ---------------------------------------------------------------------------
// finalize (split mode): out = (O0 [+ O1]) / (l0 [+ l1])
// ---------------------------------------------------------------------------
__global__ __launch_bounds__(256) void finalize(
    float* __restrict__ Om, const float* __restrict__ P1,
    const float* __restrict__ L0, const float* __restrict__ L1,
    const int* __restrict__ vlp)
{
  const int idx = blockIdx.x * 256 + threadIdx.x;   // 1,048,576 threads
  const size_t e = (size_t)idx * 4;
  const int row = (int)(e >> 7);        // b*2048 + q
  const int b = row >> 11;
  const int valid = vlp[b];
  f32x4 o = *(const f32x4*)(Om + e);
  float l = L0[row];
  if (valid > 1024) {
    const f32x4 p = *(const f32x4*)(P1 + e);
    o += p;
    l += L1[row];
  }
  const float inv = 1.0f / l;
  o *= inv;
  *(f32x4*)(Om + e) = o;
}

extern "C" void kernel_launch(void* const* d_in, const int* in_sizes, int n_in,
                              void* d_out, int out_size, void* d_ws, size_t ws_size,
                              hipStream_t stream) {
  const float* Qm = (const float*)d_in[0];
  const float* Km = (const float*)d_in[1];
  const float* Vm = (const float*)d_in[2];
  const int*   vl = (const int*)d_in[3];
  float*       Om = (float*)d_out;

  const size_t elems = (size_t)B_SZ * K_SZ * D_SZ;          // 4M
  const size_t PREP  = 3 * elems * sizeof(_Float16);        // 24MB
  const size_t HDR   = 262400;                              // cnt + L0 + L1
  const size_t P1SZ  = elems * sizeof(float);               // 16MB
  char* W = (char*)d_ws;

  if (ws_size >= HDR + PREP + P1SZ) {
    unsigned* cnt = (unsigned*)W;
    float*    L0  = (float*)(W + 256);
    float*    L1  = (float*)(W + 256 + 131072);
    _Float16* Khi = (_Float16*)(W + HDR);
    _Float16* Klo = Khi + elems;
    _Float16* Vt  = Klo + elems;
    float*    P1  = (float*)(W + HDR + PREP);
    // 3 enqueues: prep (also zeroes cnt) -> attn -> finalize
    prep_all<<<2560, 256, 0, stream>>>(Km, Vm, Khi, Klo, Vt, cnt);
    attn<<<768, 256, 0, stream>>>(Qm, Khi, Klo, Vt, vl, Om, P1, L0, L1, cnt, 1);
    finalize<<<4096, 256, 0, stream>>>(Om, P1, L0, L1, vl);
  } else {
    _Float16* Khi = (_Float16*)W;
    _Float16* Klo = Khi + elems;
    _Float16* Vt  = Klo + elems;
    prep_all<<<2560, 256, 0, stream>>>(Km, Vm, Khi, Klo, Vt, nullptr);
    attn<<<256, 256, 0, stream>>>(Qm, Khi, Klo, Vt, vl, Om,
                                  nullptr, nullptr, nullptr, nullptr, 0);
  }
}

// Round 12
// 178.062 us; speedup vs baseline: 1.7196x; 1.7196x over previous
//
#include <hip/hip_runtime.h>
#include <cmath>

typedef __attribute__((ext_vector_type(4))) float f32x4;
typedef __attribute__((ext_vector_type(8))) _Float16 f16x8;
typedef __attribute__((ext_vector_type(4))) _Float16 f16x4;
typedef __attribute__((ext_vector_type(4))) unsigned int u32x4;

#define B_SZ 16
#define Q_SZ 2048
#define K_SZ 2048
#define D_SZ 128
#define BQ   128     // q-rows per block (4 waves x 32): halves tile-units vs 64
#define BKT  64      // keys per k-tile
#define SCL  0.08838834764831845f   // fp32(1/sqrt(128))

// async global->LDS, 16B/lane: LDS dest = wave-uniform base + lane*16
#define GLDS16(g, s) __builtin_amdgcn_global_load_lds(                      \
    (const __attribute__((address_space(1))) unsigned int*)(g),             \
    (__attribute__((address_space(3))) unsigned int*)(s), 16, 0, 0)

// pack two f32 -> one u32 of 2 f16 (RNE, matches previous (_Float16) casts)
static __device__ inline unsigned pk16(float a, float b) {
  unsigned short ha = __builtin_bit_cast(unsigned short, (_Float16)a);
  unsigned short hb = __builtin_bit_cast(unsigned short, (_Float16)b);
  return (unsigned)ha | ((unsigned)hb << 16);
}

// ---------------------------------------------------------------------------
// prep_all: fused K-split + V-transpose + cnt reset.  (r9 version, verified)
// ---------------------------------------------------------------------------
__global__ __launch_bounds__(256) void prep_all(
    const float* __restrict__ K, const float* __restrict__ V,
    _Float16* __restrict__ Khi, _Float16* __restrict__ Klo,
    _Float16* __restrict__ Vt, unsigned* __restrict__ cnt)
{
  __shared__ _Float16 tmp[64][136];
  const int tid = threadIdx.x;
  if (cnt && blockIdx.x == 0 && tid == 0) *cnt = 0;
  if (blockIdx.x < 2048) {
    const int gid = blockIdx.x * 256 + tid;
    const int r = gid >> 4;           // global key row = b*2048 + k
    const int g = gid & 15;           // 16B group
    const float* src = K + (size_t)r * D_SZ + g * 8;
    f16x8 hi, lo;
#pragma unroll
    for (int i = 0; i < 8; ++i) {
      float x = src[i];
      _Float16 h = (_Float16)x;
      hi[i] = h;
      lo[i] = (_Float16)((x - (float)h) * 2048.0f);
    }
    const size_t o = (size_t)r * D_SZ + ((g ^ (r & 7)) * 8);
    *(f16x8*)(Khi + o) = hi;
    *(f16x8*)(Klo + o) = lo;
  } else {
    const int vb = blockIdx.x - 2048;
    const int b = vb >> 5;
    const int k0 = (vb & 31) * 64;
    const float* Vb = V + ((size_t)b * K_SZ + k0) * D_SZ;
#pragma unroll
    for (int j = 0; j < 8; ++j) {
      const int e = j * 1024 + tid * 4;
      const int k = e >> 7, d = e & 127;
      const f32x4 v = *(const f32x4*)(Vb + (size_t)k * D_SZ + d);
      f16x4 h;
#pragma unroll
      for (int i = 0; i < 4; ++i) h[i] = (_Float16)v[i];
      *(f16x4*)&tmp[k][d] = h;
    }
    __syncthreads();
#pragma unroll
    for (int i = 0; i < 4; ++i) {
      const int id = i * 256 + tid;
      const int gk = id >> 7, d = id & 127;   // gk = position group (0..7)
      f16x8 o;
#pragma unroll
      for (int jj = 0; jj < 8; ++jj) {
        // position p = gk*8+jj holds actual key kappa (pi-permutation)
        const int kap = ((gk >> 2) << 5) | ((jj >> 2) << 4) | ((gk & 3) << 2) | (jj & 3);
        o[jj] = tmp[kap][d];
      }
      _Float16* dst = Vt + ((size_t)b * D_SZ + d) * K_SZ + k0 + ((gk ^ (d & 7)) * 8);
      *(f16x8*)dst = o;
    }
  }
}

// ---------------------------------------------------------------------------
// attn v12 = v11 with the register budget fixed: __launch_bounds__(256, 2)
// (NOT 3 -- the (256,3) bound capped VGPRs at 84 and spilled the 64-reg
// accO to scratch; r11's 157/203MB FETCH/WRITE was spill traffic, and r5's
// was largely the same).  2 blocks/CU x 48KB LDS; grid 512.
// BQ=128 core: wave owns 32 q-rows (mt=2); each staged 48KB tile serves 2x
// the q-rows of BQ=64 -> total tile-units halve (4096), halving LDS read
// traffic and stage-DMA volume.  Sorted longest-first dynamic queue,
// plain-store half-split outputs (unique owner, no fences), finalize kernel
// = coherence point.
// ---------------------------------------------------------------------------
__global__ __launch_bounds__(256, 2) void attn(
    const float* __restrict__ Qm, const _Float16* __restrict__ KhiG,
    const _Float16* __restrict__ KloG, const _Float16* __restrict__ VtG,
    const int* __restrict__ vlp, float* __restrict__ Om,
    float* __restrict__ P1, float* __restrict__ L0, float* __restrict__ L1,
    unsigned* __restrict__ cnt, const int split)
{
  __shared__ __align__(16) char sm[49152];   // Khi(16K)|Klo(16K)|Vt(16K)
  __shared__ float Ls[128];
  __shared__ int s_task;
  __shared__ signed char ord[32];
  __shared__ int vls[16];

  const int tid  = threadIdx.x;
  const int wave = tid >> 6;
  const int lane = tid & 63;
  const int ln   = lane & 15;
  const int quad = lane >> 4;

  _Float16* smKhi = (_Float16*)sm;
  _Float16* smKlo = (_Float16*)(sm + 16384);
  _Float16* smVt  = (_Float16*)(sm + 32768);

  // ---- once per block: longest-first unit order (deterministic) ----
  if (split) {
    if (tid < 16) vls[tid] = vlp[tid];
    __syncthreads();
    if (tid < 32) {
      const int ub = tid >> 1, uh = tid & 1;
      const int v = vls[ub];
      const int n = uh ? ((v > 1024) ? (v - 1024 + 63) / 64 : 0)
                       : (((v < 1024 ? v : 1024) + 63) / 64);
      int rank = 0;
      for (int u = 0; u < 32; ++u) {
        const int wb = u >> 1, wh = u & 1;
        const int wv = vls[wb];
        const int wn = wh ? ((wv > 1024) ? (wv - 1024 + 63) / 64 : 0)
                          : (((wv < 1024 ? wv : 1024) + 63) / 64);
        rank += (wn > n) || (wn == n && u < tid);
      }
      ord[rank] = (signed char)tid;
    }
    __syncthreads();
  }

  for (;;) {
    int t;
    if (split) {
      if (tid == 0) s_task = (int)atomicAdd(cnt, 1u);
      __syncthreads();
      t = s_task;
      __syncthreads();
      if (t >= 512) return;
    } else {
      t = blockIdx.x;
    }

    int half = 0, b, qt;
    if (split) { const int u = ord[t >> 4]; b = u >> 1; half = u & 1; qt = t & 15; }
    else       { b = t >> 4; qt = t & 15; }
    const int q0     = qt * BQ;
    const int valid  = split ? vls[b] : vlp[b];
    const int kstart = half * 1024;
    const int kend   = split ? min(valid, kstart + 1024) : valid;
    if (kend <= kstart) { if (!split) return; continue; }  // empty half-1
    const int ntiles = (kend - kstart + BKT - 1) / BKT;

    const float* Qb    = Qm + (size_t)b * Q_SZ * D_SZ;
    const char*  gKhiB = (const char*)KhiG + (size_t)b * K_SZ * 256;
    const char*  gKloB = (const char*)KloG + (size_t)b * K_SZ * 256;
    const char*  gVtB  = (const char*)VtG  + (size_t)b * D_SZ * (K_SZ * 2);

    // ---- Q fragments: 2 m-tiles x 4 k-chunks, fp16 hi/lo split ----
    f16x8 qhi[2][4], qlo[2][4];
#pragma unroll
    for (int mt = 0; mt < 2; ++mt) {
      const int qrow = q0 + wave * 32 + mt * 16 + ln;
      const float* srcb = Qb + (size_t)qrow * D_SZ + quad * 8;
#pragma unroll
      for (int c = 0; c < 4; ++c) {
#pragma unroll
        for (int j = 0; j < 8; ++j) {
          float x = srcb[c * 32 + j];
          _Float16 h = (_Float16)x;
          qhi[mt][c][j] = h;
          qlo[mt][c][j] = (_Float16)((x - (float)h) * 2048.0f);
        }
      }
    }

    const f32x4 vzero = {0.f, 0.f, 0.f, 0.f};
    f32x4 accO[2][8];           // [mt][dt]: O[32q][128d] per wave
    float lsum[2] = {0.f, 0.f};
#pragma unroll
    for (int mt = 0; mt < 2; ++mt)
#pragma unroll
      for (int dt = 0; dt < 8; ++dt) accO[mt][dt] = vzero;

    for (int kt = 0; kt < ntiles; ++kt) {
      const int k0g = kstart + kt * BKT;

      if (kt) {                 // B_top: all waves done reading tile kt-1
        asm volatile("s_waitcnt lgkmcnt(0)" ::: "memory");
        __builtin_amdgcn_sched_barrier(0);
        __builtin_amdgcn_s_barrier();
        __builtin_amdgcn_sched_barrier(0);
      }

      // ---- stage tile kt (single buffer; 12 x 1KB chunks per wave) ----
      {
        const char* gh = gKhiB + (size_t)k0g * 256;
        const char* gl = gKloB + (size_t)k0g * 256;
#pragma unroll
        for (int i = 0; i < 4; ++i) {
          const int off = wave * 1024 + i * 4096;
          GLDS16(gh + off + lane * 16, sm + off);
        }
#pragma unroll
        for (int i = 0; i < 4; ++i) {
          const int off = wave * 1024 + i * 4096;
          GLDS16(gl + off + lane * 16, sm + 16384 + off);
        }
#pragma unroll
        for (int i = 0; i < 4; ++i) {
          const int off = wave * 1024 + i * 4096;
          const int a = off + lane * 16;
          const int d = a >> 7, win = a & 127;
          GLDS16(gVtB + (size_t)d * (K_SZ * 2) + (size_t)k0g * 2 + win,
                 sm + 32768 + off);
        }
      }
      asm volatile("s_waitcnt vmcnt(0)" ::: "memory");
      __builtin_amdgcn_sched_barrier(0);
      __builtin_amdgcn_s_barrier();     // B_ready: tile visible to all waves
      __builtin_amdgcn_sched_barrier(0);

      // ---- S^T = K Q^T over all 64 keys, split precision; softmax in reg ----
      f16x8 pa[2][2];           // PV A-frags [mt][hk]
#pragma unroll
      for (int hk = 0; hk < 2; ++hk) {   // key halves of 32 (= PV chunk c)
        f32x4 accM[2][2], accC[2][2];    // [mt][nb2]
#pragma unroll
        for (int mt = 0; mt < 2; ++mt)
#pragma unroll
          for (int nb2 = 0; nb2 < 2; ++nb2) { accM[mt][nb2] = vzero; accC[mt][nb2] = vzero; }
        __builtin_amdgcn_s_setprio(1);
#pragma unroll
        for (int nb2 = 0; nb2 < 2; ++nb2) {
          const int row = (hk * 2 + nb2) * 16 + ln;
          const _Float16* bh_base = smKhi + row * 128;
          const _Float16* bl_base = smKlo + row * 128;
#pragma unroll
          for (int c = 0; c < 4; ++c) {
            const int pg = (((c * 4 + quad) ^ (ln & 7)) * 8);
            const f16x8 bh = *(const f16x8*)(bh_base + pg);
            const f16x8 bl = *(const f16x8*)(bl_base + pg);
#pragma unroll
            for (int mt = 0; mt < 2; ++mt) {
              accM[mt][nb2] = __builtin_amdgcn_mfma_f32_16x16x32_f16(bh, qhi[mt][c], accM[mt][nb2], 0, 0, 0);
              accC[mt][nb2] = __builtin_amdgcn_mfma_f32_16x16x32_f16(bl, qhi[mt][c], accC[mt][nb2], 0, 0, 0);
              accC[mt][nb2] = __builtin_amdgcn_mfma_f32_16x16x32_f16(bh, qlo[mt][c], accC[mt][nb2], 0, 0, 0);
            }
          }
        }
        __builtin_amdgcn_s_setprio(0);

        // fixed-max softmax: p = e^{floor(s/sqrt d)}; masked -> 0; pack to pa
#pragma unroll
        for (int mt = 0; mt < 2; ++mt) {
          u32x4 w;
#pragma unroll
          for (int nb2 = 0; nb2 < 2; ++nb2) {
            float e[4];
#pragma unroll
            for (int r = 0; r < 4; ++r) {
              const int key = k0g + (hk * 2 + nb2) * 16 + quad * 4 + r;
              const float s = accM[mt][nb2][r] + accC[mt][nb2][r] * (1.0f / 2048.0f);
              e[r] = (key < valid) ? __expf(floorf(s * SCL)) : 0.0f;
              lsum[mt] += e[r];
            }
            w[nb2 * 2 + 0] = pk16(e[0], e[1]);
            w[nb2 * 2 + 1] = pk16(e[2], e[3]);
          }
          pa[mt][hk] = __builtin_bit_cast(f16x8, w);   // matches pi-permuted V
        }
      }

      // ---- O += P V : wave does all 128 d-cols for its 32 q-rows ----
      __builtin_amdgcn_s_setprio(1);
#pragma unroll
      for (int c = 0; c < 2; ++c) {
#pragma unroll
        for (int dt = 0; dt < 8; ++dt) {
          const int drow = dt * 16 + ln;
          const int pg = (((c * 4 + quad) ^ (ln & 7)) * 8);
          const f16x8 bf = *(const f16x8*)(smVt + drow * 64 + pg);
#pragma unroll
          for (int mt = 0; mt < 2; ++mt)
            accO[mt][dt] = __builtin_amdgcn_mfma_f32_16x16x32_f16(pa[mt][c], bf, accO[mt][dt], 0, 0, 0);
        }
      }
      __builtin_amdgcn_s_setprio(0);
    }

    // ---- epilogue: reduce l across quads (q = wave*32 + mt*16 + ln) ----
#pragma unroll
    for (int mt = 0; mt < 2; ++mt) {
      float v = lsum[mt];
      v += __shfl_xor(v, 16, 64);
      v += __shfl_xor(v, 32, 64);
      lsum[mt] = v;
    }

    if (split) {
      // plain stores: unique owner per (half,row); finalize = coherence point
      float* Lh = half ? L1 : L0;
      if (lane < 16) {
#pragma unroll
        for (int mt = 0; mt < 2; ++mt)
          Lh[b * Q_SZ + q0 + wave * 32 + mt * 16 + lane] = lsum[mt];
      }
      float* dst = (half ? P1 : Om) + ((size_t)(b * Q_SZ + q0)) * D_SZ;
#pragma unroll
      for (int mt = 0; mt < 2; ++mt)
#pragma unroll
        for (int dt = 0; dt < 8; ++dt)
#pragma unroll
          for (int r = 0; r < 4; ++r)
            dst[(size_t)(wave * 32 + mt * 16 + quad * 4 + r) * D_SZ + dt * 16 + ln] =
                accO[mt][dt][r];
    } else {
      if (lane < 16) {
#pragma unroll
        for (int mt = 0; mt < 2; ++mt)
          Ls[wave * 32 + mt * 16 + lane] = lsum[mt];
      }
      __syncthreads();
      float* Ob = Om + (size_t)b * Q_SZ * D_SZ;
#pragma unroll
      for (int mt = 0; mt < 2; ++mt) {
#pragma unroll
        for (int r = 0; r < 4; ++r) {
          const float inv = 1.0f / Ls[wave * 32 + mt * 16 + quad * 4 + r];
#pragma unroll
          for (int dt = 0; dt < 8; ++dt)
            Ob[(size_t)(q0 + wave * 32 + mt * 16 + quad * 4 + r) * D_SZ + dt * 16 + ln] =
                accO[mt][dt][r] * inv;
        }
      }
    }
    if (!split) return;
  }
}

// ---------------------------------------------------------------------------
// finalize (split mode): out = (O0 [+ O1]) / (l0 [+ l1])
// ---------------------------------------------------------------------------
__global__ __launch_bounds__(256) void finalize(
    float* __restrict__ Om, const float* __restrict__ P1,
    const float* __restrict__ L0, const float* __restrict__ L1,
    const int* __restrict__ vlp)
{
  const int idx = blockIdx.x * 256 + threadIdx.x;   // 1,048,576 threads
  const size_t e = (size_t)idx * 4;
  const int row = (int)(e >> 7);        // b*2048 + q
  const int b = row >> 11;
  const int valid = vlp[b];
  f32x4 o = *(const f32x4*)(Om + e);
  float l = L0[row];
  if (valid > 1024) {
    const f32x4 p = *(const f32x4*)(P1 + e);
    o += p;
    l += L1[row];
  }
  const float inv = 1.0f / l;
  o *= inv;
  *(f32x4*)(Om + e) = o;
}

extern "C" void kernel_launch(void* const* d_in, const int* in_sizes, int n_in,
                              void* d_out, int out_size, void* d_ws, size_t ws_size,
                              hipStream_t stream) {
  const float* Qm = (const float*)d_in[0];
  const float* Km = (const float*)d_in[1];
  const float* Vm = (const float*)d_in[2];
  const int*   vl = (const int*)d_in[3];
  float*       Om = (float*)d_out;

  const size_t elems = (size_t)B_SZ * K_SZ * D_SZ;          // 4M
  const size_t PREP  = 3 * elems * sizeof(_Float16);        // 24MB
  const size_t HDR   = 262400;                              // cnt + L0 + L1
  const size_t P1SZ  = elems * sizeof(float);               // 16MB
  char* W = (char*)d_ws;

  if (ws_size >= HDR + PREP + P1SZ) {
    unsigned* cnt = (unsigned*)W;
    float*    L0  = (float*)(W + 256);
    float*    L1  = (float*)(W + 256 + 131072);
    _Float16* Khi = (_Float16*)(W + HDR);
    _Float16* Klo = Khi + elems;
    _Float16* Vt  = Klo + elems;
    float*    P1  = (float*)(W + HDR + PREP);
    // 3 enqueues: prep (also zeroes cnt) -> attn -> finalize
    prep_all<<<2560, 256, 0, stream>>>(Km, Vm, Khi, Klo, Vt, cnt);
    attn<<<512, 256, 0, stream>>>(Qm, Khi, Klo, Vt, vl, Om, P1, L0, L1, cnt, 1);
    finalize<<<4096, 256, 0, stream>>>(Om, P1, L0, L1, vl);
  } else {
    _Float16* Khi = (_Float16*)W;
    _Float16* Klo = Khi + elems;
    _Float16* Vt  = Klo + elems;
    prep_all<<<2560, 256, 0, stream>>>(Km, Vm, Khi, Klo, Vt, nullptr);
    attn<<<256, 256, 0, stream>>>(Qm, Khi, Klo, Vt, vl, Om,
                                  nullptr, nullptr, nullptr, nullptr, 0);
  }
}

// Round 13
// 158.017 us; speedup vs baseline: 1.9377x; 1.1269x over previous
//
#include <hip/hip_runtime.h>
#include <cmath>

typedef __attribute__((ext_vector_type(4))) float f32x4;
typedef __attribute__((ext_vector_type(8))) _Float16 f16x8;
typedef __attribute__((ext_vector_type(4))) _Float16 f16x4;
typedef __attribute__((ext_vector_type(4))) unsigned int u32x4;

#define B_SZ 16
#define Q_SZ 2048
#define K_SZ 2048
#define D_SZ 128
#define BQ   64      // q-rows per block (4 waves x 16)
#define BKT  64      // keys per k-tile
#define SCL  0.08838834764831845f   // fp32(1/sqrt(128))

// async global->LDS, 16B/lane: LDS dest = wave-uniform base + lane*16
#define GLDS16(g, s) __builtin_amdgcn_global_load_lds(                      \
    (const __attribute__((address_space(1))) unsigned int*)(g),             \
    (__attribute__((address_space(3))) unsigned int*)(s), 16, 0, 0)

// pack two f32 -> one u32 of 2 f16 (RNE, matches previous (_Float16) casts)
static __device__ inline unsigned pk16(float a, float b) {
  unsigned short ha = __builtin_bit_cast(unsigned short, (_Float16)a);
  unsigned short hb = __builtin_bit_cast(unsigned short, (_Float16)b);
  return (unsigned)ha | ((unsigned)hb << 16);
}

// ---------------------------------------------------------------------------
// prep_all: fused K-split + V-transpose + cnt reset.
//  V-write COALESCED vs r9: thread -> (d = id>>3, chunk wg = id&7) so 8
//  consecutive lanes write 128 contiguous bytes of one Vt d-row (was: 16B
//  scatters at 4KB stride).  Output bytes identical (same pi-perm + swizzle).
// ---------------------------------------------------------------------------
__global__ __launch_bounds__(256) void prep_all(
    const float* __restrict__ K, const float* __restrict__ V,
    _Float16* __restrict__ Khi, _Float16* __restrict__ Klo,
    _Float16* __restrict__ Vt, unsigned* __restrict__ cnt)
{
  __shared__ _Float16 tmp[64][136];
  const int tid = threadIdx.x;
  if (cnt && blockIdx.x == 0 && tid == 0) *cnt = 0;
  if (blockIdx.x < 2048) {
    const int gid = blockIdx.x * 256 + tid;
    const int r = gid >> 4;           // global key row = b*2048 + k
    const int g = gid & 15;           // 16B group
    const float* src = K + (size_t)r * D_SZ + g * 8;
    f16x8 hi, lo;
#pragma unroll
    for (int i = 0; i < 8; ++i) {
      float x = src[i];
      _Float16 h = (_Float16)x;
      hi[i] = h;
      lo[i] = (_Float16)((x - (float)h) * 2048.0f);
    }
    const size_t o = (size_t)r * D_SZ + ((g ^ (r & 7)) * 8);
    *(f16x8*)(Khi + o) = hi;
    *(f16x8*)(Klo + o) = lo;
  } else {
    const int vb = blockIdx.x - 2048;
    const int b = vb >> 5;
    const int k0 = (vb & 31) * 64;
    const float* Vb = V + ((size_t)b * K_SZ + k0) * D_SZ;
#pragma unroll
    for (int j = 0; j < 8; ++j) {
      const int e = j * 1024 + tid * 4;
      const int k = e >> 7, d = e & 127;
      const f32x4 v = *(const f32x4*)(Vb + (size_t)k * D_SZ + d);
      f16x4 h;
#pragma unroll
      for (int i = 0; i < 4; ++i) h[i] = (_Float16)v[i];
      *(f16x4*)&tmp[k][d] = h;
    }
    __syncthreads();
#pragma unroll
    for (int i = 0; i < 4; ++i) {
      const int id = i * 256 + tid;
      const int d = id >> 3, wg = id & 7;   // 8 lanes cover one d-row's 128B
      f16x8 o;
#pragma unroll
      for (int jj = 0; jj < 8; ++jj) {
        // position p = wg*8+jj holds actual key kappa (pi-permutation)
        const int kap = ((wg >> 2) << 5) | ((jj >> 2) << 4) | ((wg & 3) << 2) | (jj & 3);
        o[jj] = tmp[kap][d];
      }
      _Float16* dst = Vt + ((size_t)b * D_SZ + d) * K_SZ + k0 + ((wg ^ (d & 7)) * 8);
      *(f16x8*)dst = o;
    }
  }
}

// ---------------------------------------------------------------------------
// attn v13 = r9 core byte-identical (best measured: BQ=64, 4 waves,
// single-buffer 48KB LDS, 3 blocks/CU, register P via swapped QK +
// pi-permuted V, sorted longest-first dynamic queue) + solo-task in-kernel
// normalization: tasks whose batch has valid<=1024 (single k-half) multiply
// accO by 1/l in-register (same f32 expression as finalize -> bit-identical)
// and write FINAL O; finalize skips those rows entirely.
// ---------------------------------------------------------------------------
__global__ __launch_bounds__(256, 3) void attn(
    const float* __restrict__ Qm, const _Float16* __restrict__ KhiG,
    const _Float16* __restrict__ KloG, const _Float16* __restrict__ VtG,
    const int* __restrict__ vlp, float* __restrict__ Om,
    float* __restrict__ P1, float* __restrict__ L0, float* __restrict__ L1,
    unsigned* __restrict__ cnt, const int split)
{
  __shared__ __align__(16) char sm[49152];   // Khi(16K)|Klo(16K)|Vt(16K)
  __shared__ float Ls[64];
  __shared__ int s_task;
  __shared__ signed char ord[32];
  __shared__ int vls[16];

  const int tid  = threadIdx.x;
  const int wave = tid >> 6;
  const int lane = tid & 63;
  const int ln   = lane & 15;
  const int quad = lane >> 4;

  _Float16* smKhi = (_Float16*)sm;
  _Float16* smKlo = (_Float16*)(sm + 16384);
  _Float16* smVt  = (_Float16*)(sm + 32768);

  // ---- once per block: longest-first unit order (deterministic) ----
  if (split) {
    if (tid < 16) vls[tid] = vlp[tid];
    __syncthreads();
    if (tid < 32) {
      const int ub = tid >> 1, uh = tid & 1;
      const int v = vls[ub];
      const int n = uh ? ((v > 1024) ? (v - 1024 + 63) / 64 : 0)
                       : (((v < 1024 ? v : 1024) + 63) / 64);
      int rank = 0;
      for (int u = 0; u < 32; ++u) {
        const int wb = u >> 1, wh = u & 1;
        const int wv = vls[wb];
        const int wn = wh ? ((wv > 1024) ? (wv - 1024 + 63) / 64 : 0)
                          : (((wv < 1024 ? wv : 1024) + 63) / 64);
        rank += (wn > n) || (wn == n && u < tid);
      }
      ord[rank] = (signed char)tid;
    }
    __syncthreads();
  }

  for (;;) {
    int t;
    if (split) {
      if (tid == 0) s_task = (int)atomicAdd(cnt, 1u);
      __syncthreads();
      t = s_task;
      __syncthreads();
      if (t >= 1024) return;
    } else {
      t = blockIdx.x;
    }

    int half = 0, b, qt;
    if (split) { const int u = ord[t >> 5]; b = u >> 1; half = u & 1; qt = t & 31; }
    else       { b = t >> 5; qt = t & 31; }
    const int q0     = qt * BQ;
    const int valid  = split ? vls[b] : vlp[b];
    const int kstart = half * 1024;
    const int kend   = split ? min(valid, kstart + 1024) : valid;
    if (kend <= kstart) { if (!split) return; continue; }  // empty half-1
    const int ntiles = (kend - kstart + BKT - 1) / BKT;

    const float* Qb    = Qm + (size_t)b * Q_SZ * D_SZ;
    const char*  gKhiB = (const char*)KhiG + (size_t)b * K_SZ * 256;
    const char*  gKloB = (const char*)KloG + (size_t)b * K_SZ * 256;
    const char*  gVtB  = (const char*)VtG  + (size_t)b * D_SZ * (K_SZ * 2);

    // ---- Q fragments: 4 k-chunks, fp16 hi/lo split (16 rows/wave) ----
    f16x8 qhi[4], qlo[4];
    {
      const int qrow = q0 + wave * 16 + ln;
      const float* srcb = Qb + (size_t)qrow * D_SZ + quad * 8;
#pragma unroll
      for (int c = 0; c < 4; ++c) {
#pragma unroll
        for (int j = 0; j < 8; ++j) {
          float x = srcb[c * 32 + j];
          _Float16 h = (_Float16)x;
          qhi[c][j] = h;
          qlo[c][j] = (_Float16)((x - (float)h) * 2048.0f);
        }
      }
    }

    const f32x4 vzero = {0.f, 0.f, 0.f, 0.f};
    f32x4 accO[8];              // [dt]: O[16q][128d] per wave
    float lsum = 0.0f;
#pragma unroll
    for (int dt = 0; dt < 8; ++dt) accO[dt] = vzero;

    for (int kt = 0; kt < ntiles; ++kt) {
      const int k0g = kstart + kt * BKT;

      if (kt) {                 // B_top: all waves done reading tile kt-1
        asm volatile("s_waitcnt lgkmcnt(0)" ::: "memory");
        __builtin_amdgcn_sched_barrier(0);
        __builtin_amdgcn_s_barrier();
        __builtin_amdgcn_sched_barrier(0);
      }

      // ---- stage tile kt (single buffer; 12 x 1KB chunks per wave) ----
      {
        const char* gh = gKhiB + (size_t)k0g * 256;
        const char* gl = gKloB + (size_t)k0g * 256;
#pragma unroll
        for (int i = 0; i < 4; ++i) {
          const int off = wave * 1024 + i * 4096;
          GLDS16(gh + off + lane * 16, sm + off);
        }
#pragma unroll
        for (int i = 0; i < 4; ++i) {
          const int off = wave * 1024 + i * 4096;
          GLDS16(gl + off + lane * 16, sm + 16384 + off);
        }
#pragma unroll
        for (int i = 0; i < 4; ++i) {
          const int off = wave * 1024 + i * 4096;
          const int a = off + lane * 16;
          const int d = a >> 7, win = a & 127;
          GLDS16(gVtB + (size_t)d * (K_SZ * 2) + (size_t)k0g * 2 + win,
                 sm + 32768 + off);
        }
      }
      asm volatile("s_waitcnt vmcnt(0)" ::: "memory");
      __builtin_amdgcn_sched_barrier(0);
      __builtin_amdgcn_s_barrier();     // B_ready: tile visible to all waves
      __builtin_amdgcn_sched_barrier(0);

      // ---- S^T = K Q^T over all 64 keys, split precision; softmax in reg ----
      f16x8 pa[2];              // PV A-frags [hk]
#pragma unroll
      for (int hk = 0; hk < 2; ++hk) {   // key halves of 32 (= PV chunk c)
        f32x4 accM[2], accC[2];
#pragma unroll
        for (int nb2 = 0; nb2 < 2; ++nb2) { accM[nb2] = vzero; accC[nb2] = vzero; }
        __builtin_amdgcn_s_setprio(1);
#pragma unroll
        for (int nb2 = 0; nb2 < 2; ++nb2) {
          const int row = (hk * 2 + nb2) * 16 + ln;
          const _Float16* bh_base = smKhi + row * 128;
          const _Float16* bl_base = smKlo + row * 128;
#pragma unroll
          for (int c = 0; c < 4; ++c) {
            const int pg = (((c * 4 + quad) ^ (ln & 7)) * 8);
            const f16x8 bh = *(const f16x8*)(bh_base + pg);
            const f16x8 bl = *(const f16x8*)(bl_base + pg);
            accM[nb2] = __builtin_amdgcn_mfma_f32_16x16x32_f16(bh, qhi[c], accM[nb2], 0, 0, 0);
            accC[nb2] = __builtin_amdgcn_mfma_f32_16x16x32_f16(bl, qhi[c], accC[nb2], 0, 0, 0);
            accC[nb2] = __builtin_amdgcn_mfma_f32_16x16x32_f16(bh, qlo[c], accC[nb2], 0, 0, 0);
          }
        }
        __builtin_amdgcn_s_setprio(0);

        // fixed-max softmax: p = e^{floor(s/sqrt d)}; masked -> 0; pack to pa
        u32x4 w;
#pragma unroll
        for (int nb2 = 0; nb2 < 2; ++nb2) {
          float e[4];
#pragma unroll
          for (int r = 0; r < 4; ++r) {
            const int key = k0g + (hk * 2 + nb2) * 16 + quad * 4 + r;
            const float s = accM[nb2][r] + accC[nb2][r] * (1.0f / 2048.0f);
            e[r] = (key < valid) ? __expf(floorf(s * SCL)) : 0.0f;
            lsum += e[r];
          }
          w[nb2 * 2 + 0] = pk16(e[0], e[1]);
          w[nb2 * 2 + 1] = pk16(e[2], e[3]);
        }
        pa[hk] = __builtin_bit_cast(f16x8, w);   // matches pi-permuted V
      }

      // ---- O += P V : wave does all 128 d-cols for its 16 q-rows ----
      __builtin_amdgcn_s_setprio(1);
#pragma unroll
      for (int c = 0; c < 2; ++c) {
#pragma unroll
        for (int dt = 0; dt < 8; ++dt) {
          const int drow = dt * 16 + ln;
          const int pg = (((c * 4 + quad) ^ (ln & 7)) * 8);
          const f16x8 bf = *(const f16x8*)(smVt + drow * 64 + pg);
          accO[dt] = __builtin_amdgcn_mfma_f32_16x16x32_f16(pa[c], bf, accO[dt], 0, 0, 0);
        }
      }
      __builtin_amdgcn_s_setprio(0);
    }

    // ---- epilogue: reduce l across quads (q = wave*16 + ln) ----
    {
      float v = lsum;
      v += __shfl_xor(v, 16, 64);
      v += __shfl_xor(v, 32, 64);
      lsum = v;
    }

    if (split) {
      if (valid <= 1024) {
        // solo task (only half-0 exists): normalize in-kernel, write FINAL O.
        // inv = 1.0f/l with identical bits to the finalize path.
        float* Ob = Om + (size_t)b * Q_SZ * D_SZ;
#pragma unroll
        for (int r = 0; r < 4; ++r) {
          const float inv = 1.0f / __shfl(lsum, quad * 4 + r, 64);
#pragma unroll
          for (int dt = 0; dt < 8; ++dt)
            Ob[(size_t)(q0 + wave * 16 + quad * 4 + r) * D_SZ + dt * 16 + ln] =
                accO[dt][r] * inv;
        }
      } else {
        // two-half batch: plain partial stores (unique owner per (half,row));
        // finalize kernel = coherence point
        float* Lh = half ? L1 : L0;
        if (lane < 16)
          Lh[b * Q_SZ + q0 + wave * 16 + lane] = lsum;
        float* dst = (half ? P1 : Om) + ((size_t)(b * Q_SZ + q0)) * D_SZ;
#pragma unroll
        for (int dt = 0; dt < 8; ++dt)
#pragma unroll
          for (int r = 0; r < 4; ++r)
            dst[(size_t)(wave * 16 + quad * 4 + r) * D_SZ + dt * 16 + ln] =
                accO[dt][r];
      }
    } else {
      if (lane < 16) Ls[wave * 16 + lane] = lsum;
      __syncthreads();
      float* Ob = Om + (size_t)b * Q_SZ * D_SZ;
#pragma unroll
      for (int r = 0; r < 4; ++r) {
        const float inv = 1.0f / Ls[wave * 16 + quad * 4 + r];
#pragma unroll
        for (int dt = 0; dt < 8; ++dt)
          Ob[(size_t)(q0 + wave * 16 + quad * 4 + r) * D_SZ + dt * 16 + ln] =
              accO[dt][r] * inv;
      }
    }
    if (!split) return;
  }
}

// ---------------------------------------------------------------------------
// finalize (split mode): only rows of two-half batches need combining;
// solo-batch rows (valid<=1024) were finalized in attn -> early return.
// ---------------------------------------------------------------------------
__global__ __launch_bounds__(256) void finalize(
    float* __restrict__ Om, const float* __restrict__ P1,
    const float* __restrict__ L0, const float* __restrict__ L1,
    const int* __restrict__ vlp)
{
  const int idx = blockIdx.x * 256 + threadIdx.x;   // 1,048,576 threads
  const size_t e = (size_t)idx * 4;
  const int row = (int)(e >> 7);        // b*2048 + q
  const int b = row >> 11;
  const int valid = vlp[b];
  if (valid <= 1024) return;            // already final (attn solo path)
  f32x4 o = *(const f32x4*)(Om + e);
  float l = L0[row];
  const f32x4 p = *(const f32x4*)(P1 + e);
  o += p;
  l += L1[row];
  const float inv = 1.0f / l;
  o *= inv;
  *(f32x4*)(Om + e) = o;
}

extern "C" void kernel_launch(void* const* d_in, const int* in_sizes, int n_in,
                              void* d_out, int out_size, void* d_ws, size_t ws_size,
                              hipStream_t stream) {
  const float* Qm = (const float*)d_in[0];
  const float* Km = (const float*)d_in[1];
  const float* Vm = (const float*)d_in[2];
  const int*   vl = (const int*)d_in[3];
  float*       Om = (float*)d_out;

  const size_t elems = (size_t)B_SZ * K_SZ * D_SZ;          // 4M
  const size_t PREP  = 3 * elems * sizeof(_Float16);        // 24MB
  const size_t HDR   = 262400;                              // cnt + L0 + L1
  const size_t P1SZ  = elems * sizeof(float);               // 16MB
  char* W = (char*)d_ws;

  if (ws_size >= HDR + PREP + P1SZ) {
    unsigned* cnt = (unsigned*)W;
    float*    L0  = (float*)(W + 256);
    float*    L1  = (float*)(W + 256 + 131072);
    _Float16* Khi = (_Float16*)(W + HDR);
    _Float16* Klo = Khi + elems;
    _Float16* Vt  = Klo + elems;
    float*    P1  = (float*)(W + HDR + PREP);
    // 3 enqueues: prep (also zeroes cnt) -> attn -> finalize
    prep_all<<<2560, 256, 0, stream>>>(Km, Vm, Khi, Klo, Vt, cnt);
    attn<<<768, 256, 0, stream>>>(Qm, Khi, Klo, Vt, vl, Om, P1, L0, L1, cnt, 1);
    finalize<<<4096, 256, 0, stream>>>(Om, P1, L0, L1, vl);
  } else {
    _Float16* Khi = (_Float16*)W;
    _Float16* Klo = Khi + elems;
    _Float16* Vt  = Klo + elems;
    prep_all<<<2560, 256, 0, stream>>>(Km, Vm, Khi, Klo, Vt, nullptr);
    attn<<<512, 256, 0, stream>>>(Qm, Khi, Klo, Vt, vl, Om,
                                  nullptr, nullptr, nullptr, nullptr, 0);
  }
}